// Round 15
// baseline (872.258 us; speedup 1.0000x reference)
//
#include <hip/hip_runtime.h>
#include <hip/hip_bf16.h>

typedef __attribute__((ext_vector_type(4))) float f4;
typedef __attribute__((ext_vector_type(4))) short s4;
typedef __attribute__((ext_vector_type(8))) short s8;

#define SEQ 4096
#define DIM 1024
#define NB 8

__device__ inline short f2bf(float f) {
    return __builtin_bit_cast(short, __float2bfloat16(f));
}

__device__ inline float bf2f(short s) {
    return __builtin_bit_cast(float, (unsigned)((unsigned short)s) << 16);
}

__device__ inline void gload_lds16(const void* g, void* l) {
    __builtin_amdgcn_global_load_lds(
        (const __attribute__((address_space(1))) void*)g,
        (__attribute__((address_space(3))) void*)l, 16, 0, 0);
}

// ===========================================================================
// gemmB: C[M,N] = A[M,K] * B[N,K]^T. bf16 in, fp32 accum.
// Tile 128x256, BK=32, 8 waves (2Mx4N, per-wave 64x64 out, acc 64 VGPR).
// Ring-2 drain schedule (validated r6/r13): STAGE(t+1) before compute of
// tile t, one __syncthreads per K-step. LDS = 2 x 24 KB = 48 KB -> 2
// blocks/CU co-resident (the m97 TLP mechanism): the other block's compute
// hides this block's drain stall. All call-site grids >= 512.
// LDS row = 32 shorts (64 B), 4 chunks of 16 B; slot s at row r holds
// global chunk s ^ ((r>>1)&3) (round-6 zero-conflict involution).
// Batched via blockIdx.y (ELEMENT strides). OUT: 0 = fp32 (+bias), 2 = bf16.
// ===========================================================================
template<int OUT>
__global__ __launch_bounds__(512, 4) void gemmB(
    const short* __restrict__ A, size_t lda, size_t bsA,
    const short* __restrict__ B, size_t ldb, size_t bsB,
    void* __restrict__ C, size_t ldc, size_t bsC,
    const float* __restrict__ bias, int nt, int gridN)
{
    __shared__ short lds[2 * 12288];   // per buf: A 4096 + B 8192 shorts
    const int tid  = threadIdx.x;
    const int lane = tid & 63;
    const int wave = tid >> 6;

    A += (size_t)blockIdx.y * bsA;
    B += (size_t)blockIdx.y * bsB;
    float* Cf = (float*)C + (size_t)blockIdx.y * bsC;
    short* Cs = (short*)C + (size_t)blockIdx.y * bsC;

    const int nwg = gridDim.x;
    int wg = blockIdx.x;
    wg = (wg & 7) * (nwg >> 3) + (wg >> 3);   // bijective (nwg % 8 == 0)
    const size_t tm = (size_t)(wg / gridN) * 128;
    const size_t tn = (size_t)(wg % gridN) * 256;

    // Staging: A row = tid>>2 (0..127), chunk = tid&3; B rows tid>>2 + j*128.
    // Source chunk sc = (tid&3) ^ ((tid>>3)&3), j-invariant (128>>1 ≡ 0 mod 4).
    // LDS dest is linear: tid*8 shorts (16 B/lane).
    const int srow = tid >> 2;
    const int sc   = (tid & 3) ^ ((tid >> 3) & 3);
    const short* pA = A + (tm + srow) * lda + sc * 8;
    const short* pB = B + (tn + srow) * ldb + sc * 8;
    const size_t b128 = (size_t)128 * ldb;

    const int fr = lane & 15, kg = lane >> 4;
    const int ck = kg ^ ((fr >> 1) & 3);       // read-slot swizzle
    const int wr = wave >> 2, wc = wave & 3;   // 2M x 4N

    auto STAGE = [&](int t) {
        short* buf = lds + (t & 1) * 12288;
        const size_t k0 = (size_t)t * 32;
        gload_lds16(pA + k0,        buf + tid * 8);
        gload_lds16(pB + k0,        buf + 4096 + tid * 8);
        gload_lds16(pB + b128 + k0, buf + 8192 + tid * 8);
    };

    f4 acc[4][4];
    #pragma unroll
    for (int m = 0; m < 4; ++m)
        #pragma unroll
        for (int n = 0; n < 4; ++n)
            acc[m][n] = (f4){0.f, 0.f, 0.f, 0.f};

    STAGE(0);
    __syncthreads();

    for (int t = 0; t < nt; ++t) {
        if (t + 1 < nt) STAGE(t + 1);

        const short* bufA = lds + (t & 1) * 12288;
        const short* bufB = bufA + 4096;
        s8 af[4], bf[4];
        #pragma unroll
        for (int m = 0; m < 4; ++m) {
            const int row = wr * 64 + m * 16 + fr;
            af[m] = *(const s8*)(bufA + row * 32 + ck * 8);
        }
        #pragma unroll
        for (int n = 0; n < 4; ++n) {
            const int row = wc * 64 + n * 16 + fr;
            bf[n] = *(const s8*)(bufB + row * 32 + ck * 8);
        }
        __builtin_amdgcn_s_setprio(1);
        #pragma unroll
        for (int m = 0; m < 4; ++m)
            #pragma unroll
            for (int n = 0; n < 4; ++n)
                acc[m][n] = __builtin_amdgcn_mfma_f32_16x16x32_bf16(
                    af[m], bf[n], acc[m][n], 0, 0, 0);
        __builtin_amdgcn_s_setprio(0);

        __syncthreads();
    }

    const int cg = lane >> 4, cl = lane & 15;
    #pragma unroll
    for (int m = 0; m < 4; ++m) {
        #pragma unroll
        for (int n = 0; n < 4; ++n) {
            const size_t grow = tm + wr * 64 + m * 16 + cg * 4;
            const size_t gcol = tn + wc * 64 + n * 16 + cl;
            float bv = 0.f;
            if constexpr (OUT == 0) { if (bias) bv = bias[gcol]; }
            #pragma unroll
            for (int i = 0; i < 4; ++i) {
                const float val = acc[m][n][i] + bv;
                if constexpr (OUT == 0)
                    Cf[(grow + i) * ldc + gcol] = val;
                else
                    Cs[(grow + i) * ldc + gcol] = f2bf(val);
            }
        }
    }
}

// fp32 -> bf16, 8 elements/thread (W only).
__global__ __launch_bounds__(256) void conv_bf16(const float* __restrict__ in,
                                                 short* __restrict__ out, int n8)
{
    const int i = blockIdx.x * 256 + threadIdx.x;
    if (i >= n8) return;
    f4 a = ((const f4*)in)[2 * i];
    f4 b = ((const f4*)in)[2 * i + 1];
    s8 w;
    w[0] = f2bf(a[0]); w[1] = f2bf(a[1]); w[2] = f2bf(a[2]); w[3] = f2bf(a[3]);
    w[4] = f2bf(b[0]); w[5] = f2bf(b[1]); w[6] = f2bf(b[2]); w[7] = f2bf(b[3]);
    ((s8*)out)[i] = w;
}

// ===========================================================================
// prep_batch: one launch per batch doing Q-conv, K-conv, V-transpose.
// ===========================================================================
__global__ __launch_bounds__(256) void prep_batch(
    const float* __restrict__ Qf, const float* __restrict__ Kf,
    const float* __restrict__ Vf,
    short* __restrict__ Qb, short* __restrict__ Kb, short* __restrict__ VT)
{
    const int tid = threadIdx.x;
    const int blk = blockIdx.x;

    if (blk < 4096) {
        const float* in = (blk < 2048) ? Qf : Kf;
        short* out      = (blk < 2048) ? Qb : Kb;
        const int i = (blk & 2047) * 256 + tid;
        f4 a = ((const f4*)in)[2 * i];
        f4 b = ((const f4*)in)[2 * i + 1];
        s8 w;
        w[0] = f2bf(a[0]); w[1] = f2bf(a[1]); w[2] = f2bf(a[2]); w[3] = f2bf(a[3]);
        w[4] = f2bf(b[0]); w[5] = f2bf(b[1]); w[6] = f2bf(b[2]); w[7] = f2bf(b[3]);
        ((s8*)out)[i] = w;
    } else {
        __shared__ float t[32][33];
        const int b2 = blk - 4096;
        const size_t k0 = (size_t)(b2 & 127) * 32;
        const size_t d0 = (size_t)(b2 >> 7) * 32;

        const int r = tid >> 3, c4 = (tid & 7) * 4;
        f4 x = *(const f4*)(Vf + (k0 + r) * DIM + d0 + c4);
        #pragma unroll
        for (int i = 0; i < 4; ++i) t[r][c4 + i] = x[i];
        __syncthreads();

        const int d = tid >> 3, kk = (tid & 7) * 4;
        s4 w;
        #pragma unroll
        for (int i = 0; i < 4; ++i) w[i] = f2bf(t[kk + i][d]);
        *(s4*)(VT + (d0 + d) * SEQ + k0 + kk) = w;
    }
}

// Row softmax over 4096 bf16 scores (packed, ld 4096), y-batched over 4
// score slices of SEQ*SEQ. Validated structure (rounds 12/13).
__global__ __launch_bounds__(256) void softmax_rows_bf(short* __restrict__ scores)
{
    const int tid = threadIdx.x;
    short* srow = scores + (size_t)blockIdx.y * SEQ * SEQ + (size_t)blockIdx.x * SEQ;
    const float SCALE = 0.03125f;

    float v[16];
    float mx = -3.4e38f;
    #pragma unroll
    for (int j = 0; j < 4; ++j) {
        s4 h = *(const s4*)(srow + (size_t)(j * 256 + tid) * 4);
        #pragma unroll
        for (int i = 0; i < 4; ++i) {
            const float f = bf2f(h[i]) * SCALE;
            v[j * 4 + i] = f;
            mx = fmaxf(mx, f);
        }
    }
    #pragma unroll
    for (int o = 32; o > 0; o >>= 1) mx = fmaxf(mx, __shfl_xor(mx, o));
    __shared__ float red[4];
    if ((tid & 63) == 0) red[tid >> 6] = mx;
    __syncthreads();
    mx = fmaxf(fmaxf(red[0], red[1]), fmaxf(red[2], red[3]));

    float sum = 0.f;
    #pragma unroll
    for (int j = 0; j < 16; ++j) {
        const float e = __expf(v[j] - mx);
        v[j] = e;
        sum += e;
    }
    #pragma unroll
    for (int o = 32; o > 0; o >>= 1) sum += __shfl_xor(sum, o);
    __syncthreads();
    if ((tid & 63) == 0) red[tid >> 6] = sum;
    __syncthreads();
    const float inv = 1.f / (red[0] + red[1] + red[2] + red[3]);

    #pragma unroll
    for (int j = 0; j < 4; ++j) {
        s4 w;
        #pragma unroll
        for (int i = 0; i < 4; ++i) w[i] = f2bf(v[j * 4 + i] * inv);
        *(s4*)(srow + (size_t)(j * 256 + tid) * 4) = w;
    }
}

extern "C" void kernel_launch(void* const* d_in, const int* in_sizes, int n_in,
                              void* d_out, int out_size, void* d_ws, size_t ws_size,
                              hipStream_t stream) {
    const float* Q    = (const float*)d_in[0];
    const float* Km   = (const float*)d_in[1];
    const float* V    = (const float*)d_in[2];
    const float* W    = (const float*)d_in[3];
    const float* bias = (const float*)d_in[4];
    float* out = (float*)d_out;

    // ws: ctx bf16 64MB | VT4 32MB | Qb 8MB | Kb 8MB | Wb 2MB  (= 114 MB)
    short* ctx = (short*)d_ws;
    short* VT4 = ctx + (size_t)NB * SEQ * DIM;
    short* Qb  = VT4 + (size_t)4 * DIM * SEQ;
    short* Kb  = Qb + (size_t)SEQ * DIM;
    short* Wb  = Kb + (size_t)SEQ * DIM;
    // d_out holds bf16 scores for a group of 4 batches (4 x 32 MB = 128 MiB).
    short* scoresB = (short*)d_out;

    const dim3 blk256(256), blk512(512);
    conv_bf16<<<DIM * DIM / 2048, blk256, 0, stream>>>(W, Wb, DIM * DIM / 8);

    for (int g = 0; g < 2; ++g) {
        for (int b4 = 0; b4 < 4; ++b4) {
            const int b = g * 4 + b4;
            const float* Qf = Q  + (size_t)b * SEQ * DIM;
            const float* Kf = Km + (size_t)b * SEQ * DIM;
            const float* Vf = V  + (size_t)b * SEQ * DIM;

            prep_batch<<<dim3(8192), blk256, 0, stream>>>(
                Qf, Kf, Vf, Qb, Kb, VT4 + (size_t)b4 * DIM * SEQ);

            // scores(bf16, raw) = Qb * Kb^T into slice b4; grid 32M x 16N = 512
            gemmB<2><<<dim3(512, 1), blk512, 0, stream>>>(
                Qb, DIM, 0, Kb, DIM, 0,
                scoresB + (size_t)b4 * SEQ * SEQ, SEQ, 0,
                nullptr, DIM / 32, 16);
        }
        softmax_rows_bf<<<dim3(SEQ, 4), blk256, 0, stream>>>(scoresB);

        // ctx = P * VT^T, y-batched over 4: grid (32M x 4N) x 4 = 512 wgs
        gemmB<2><<<dim3(128, 4), blk512, 0, stream>>>(
            scoresB, SEQ, (size_t)SEQ * SEQ,
            VT4, SEQ, (size_t)DIM * SEQ,
            ctx + (size_t)g * 4 * SEQ * DIM, DIM, (size_t)SEQ * DIM,
            nullptr, SEQ / 32, 4);
    }

    // proj: out = ctx * W^T + bias; grid 256M x 4N = 1024 wgs
    gemmB<0><<<dim3(1024, 1), blk512, 0, stream>>>(
        ctx, DIM, 0, Wb, DIM, 0, out, DIM, 0, bias, DIM / 32, 4);
}